// Round 4
// baseline (153.126 us; speedup 1.0000x reference)
//
#include <hip/hip_runtime.h>
#include <hip/hip_fp16.h>
#include <math.h>

// Problem constants (B=8, S=2048, T=128)
#define S_LEN 2048
#define T_DIM 128
#define BM 128               // tokens per block (m-range): Mt=4 m-tiles
#define TN 64                // output cols per block: Nt=2 t-tiles
#define NBLK 256             // (mb 0..127) x (th 0..1); th on bit0 -> XCD-pinned
#define TOKR 132             // tokT2 row stride in f16 (264 B)
#define RING_OFF 34816       // ring base byte offset in smem (16B aligned)
#define SLOT_B 2048          // bytes per ring slot (2 fragments x 1KB)

typedef _Float16 half8 __attribute__((ext_vector_type(8)));
typedef _Float16 half4t __attribute__((ext_vector_type(4)));
typedef float floatx16 __attribute__((ext_vector_type(16)));
typedef unsigned int u32;

// Fast exact tanh: 1 - 2/(1+e^{2x})
__device__ __forceinline__ float tanh_fast(float x) {
  return 1.0f - __fdividef(2.0f, 1.0f + __expf(2.0f * x));
}

// global->LDS DMA, 16B/lane, dest = wave-uniform base + lane*16 (HW rule)
__device__ __forceinline__ void load_lds16(const void* g, void* l) {
  __builtin_amdgcn_global_load_lds(
      (const __attribute__((address_space(1))) u32*)g,
      (__attribute__((address_space(3))) u32*)l, 16, 0, 0);
}

#define VM() asm volatile("s_waitcnt vmcnt(8)" ::: "memory")

// ---------------------------------------------------------------------------
// Kernel A (grid 3072x256): fused prep (unchanged):
//  blocks 0..1023  : W fp32 [t][p][q] -> W16f fp16 MFMA-fragment order
//  blocks 1024..3071: out[b,i,t] = sum(w_red)*tanh(b_comp[t]) + b_red
// ---------------------------------------------------------------------------
__global__ __launch_bounds__(256) void prep_kernel(
    const float* __restrict__ W, const float* __restrict__ w_red,
    const float* __restrict__ b_comp, const float* __restrict__ b_red,
    _Float16* __restrict__ W16f, float* __restrict__ out) {
  const int blk = blockIdx.x;
  const int tid = threadIdx.x;
  if (blk < 1024) {
    const int t = blk >> 3;
    const int qh = (blk >> 2) & 1;
    const int it = blk & 3;
    const int tc = t >> 5, tl = t & 31;
    const int e8 = it * 256 + tid;        // 0..1023 over [p(128)][q-chunk(8)]
    const int p = e8 >> 3;
    const int q = qh * 64 + (e8 & 7) * 8;
    const float* src = W + (size_t)t * 16384 + (size_t)p * 128 + q;
    const float4 v0 = *(const float4*)src;
    const float4 v1 = *(const float4*)(src + 4);
    half8 h;
    h[0] = (_Float16)v0.x; h[1] = (_Float16)v0.y;
    h[2] = (_Float16)v0.z; h[3] = (_Float16)v0.w;
    h[4] = (_Float16)v1.x; h[5] = (_Float16)v1.y;
    h[6] = (_Float16)v1.z; h[7] = (_Float16)v1.w;
    const int kc = q >> 4, lh2 = (q >> 3) & 1;
    *(half8*)(W16f + ((size_t)((p * 4 + tc) * 8 + kc)) * 512 + lh2 * 256 + tl * 8) = h;
  } else {
    __shared__ float red4[4];
    float part = 0.f;
#pragma unroll
    for (int i = 0; i < 8; ++i) part += w_red[tid * 8 + i];
#pragma unroll
    for (int off = 32; off > 0; off >>= 1) part += __shfl_down(part, off, 64);
    if ((tid & 63) == 0) red4[tid >> 6] = part;
    __syncthreads();
    const float Sw = red4[0] + red4[1] + red4[2] + red4[3];
    const float br = b_red[0];
    const size_t base = (size_t)(blk - 1024) * 1024 + (size_t)tid * 4;
    const int t0 = (int)(base & 127);
    float4 v;
    v.x = Sw * tanh_fast(b_comp[t0 + 0]) + br;
    v.y = Sw * tanh_fast(b_comp[t0 + 1]) + br;
    v.z = Sw * tanh_fast(b_comp[t0 + 2]) + br;
    v.w = Sw * tanh_fast(b_comp[t0 + 3]) + br;
    *(float4*)(out + base) = v;
  }
}

// ---------------------------------------------------------------------------
// Kernel B: MFMA main, BM=128 x TN=64, wave-private depth-6 LDS ring.
// R4 THEORY: R1/R3 falsified BW theories (MfmaUtil pinned ~46% across wave
// counts & traffic levels; L1 rate only ~12 B/cyc at T=1350). Fit: per-wave
// load-latency exposure that a register pipeline (depth<=3, reg-capped at
// 224/wave) cannot cover. Fix = T3/T4 pattern: global_load_lds DMA into a
// per-wave-private 6-deep LDS ring (8 waves x 6 x 2KB = 96KB), constant
// counted s_waitcnt vmcnt(8) (never 0), fragments consumed by ds_read_b128
// with distance-1 register prefetch. Wave-private => NO barriers in loop.
// In-flight ~80KB/CU covers ~2600cyc latency. W16f fragment order is already
// lane*16-contiguous => DMA source coalesced 1KB/wave-inst, LDS linear dest.
// LDS: tokT2 34KB + ring 96KB = 130KB; red (64KB) ALIASES [0..64KB) after
// the post-loop barrier (ring dead; junk wrapped DMAs drained AT barrier
// before first red write). 1 block/CU, 2 waves/SIMD (reg-bound: 128 AGPR acc).
// vmcnt(8) invariant: loads for step k issued end of step k-6; at step k's
// wait, younger DMAs = steps k+2..k+5 = 8 => vmcnt(8) guarantees step k+1's
// slot complete before its ds_read. Per-wave in-order completion [m135].
// v_mfma_f32_32x32x16_f16: A lane m=l&31, k=(l>>5)*8+j; B n=l&31 same k;
// C/D col=l&31, row=(r&3)+8*(r>>2)+4*(l>>5)   [m74/m101-verified]
// ---------------------------------------------------------------------------
__global__ __launch_bounds__(512, 2) void main_kernel(
    const float* __restrict__ tok, const int* __restrict__ heads,
    const _Float16* __restrict__ W16f, const float* __restrict__ b_comp,
    const float* __restrict__ w_red, float* __restrict__ out) {
  __shared__ __align__(16) char smem[133120];  // 130 KB: tokT2 | ring ; red aliases
  _Float16* const tokT2 = (_Float16*)smem;     // 33.8 KB: [p][(mi ^ swz(p))]
  float* const red0 = (float*)smem;            // epilogue alias, plane 0 (32 KB)
  float* const red1 = (float*)smem + BM * TN;  // plane 1 (32 KB)

  const int tid = threadIdx.x;
  const int lane = tid & 63;
  const int kh = tid >> 6;   // wave = q-chunk of 16 (kc index)
  const int l31 = lane & 31;
  const int lh = lane >> 5;
  const int blk = blockIdx.x;
  const int th = blk & 1;                 // t-half, bit0 (XCD-pinned: XCD=blk&7)
  const int mb = blk >> 1;                // 0..127
  // Full-rank p-phase stagger per XCD (L2 decorrelation, R1-proven +8%)
  const int pstag = ((blk >> 3) * 4) & 127;
  const size_t tokbase = (size_t)mb * BM * T_DIM;

  // Per-wave ring base + DMA source lane pointers (fragment order: lane*16)
  char* const ringp = smem + RING_OFF + kh * (6 * SLOT_B);
  const char* const wsrc0 =
      (const char*)W16f + (size_t)(th * 2 + 0) * 8192 + kh * 1024 + lane * 16;
  const char* const wsrc1 =
      (const char*)W16f + (size_t)(th * 2 + 1) * 8192 + kh * 1024 + lane * 16;

  auto issue = [&](int step, int slot) {
    const size_t pb = (size_t)((step + pstag) & 127) * 32768;
    load_lds16(wsrc0 + pb, ringp + slot * SLOT_B);
    load_lds16(wsrc1 + pb, ringp + slot * SLOT_B + 1024);
  };
  auto readF = [&](half8 (&bf)[2], int slot) {
    bf[0] = *(const half8*)(ringp + slot * SLOT_B + lane * 16);
    bf[1] = *(const half8*)(ringp + slot * SLOT_B + 1024 + lane * 16);
  };
  auto readT = [&](half4t& tk, int step) {
    const int pp = (step + pstag) & 127;
    const int col = (l31 * 4) ^ (((pp + (pp >> 3)) & 7) << 2);
    tk = *(const half4t*)(tokT2 + pp * TOKR + col);
  };

  // ---- issue ring prologue FIRST (latency hides under staging) ----
#pragma unroll
  for (int s = 0; s < 6; ++s) issue(s, s);

  // ---- stage tokT2: coalesced float4 reads, swizzled transposed f16 writes --
#pragma unroll
  for (int it = 0; it < 8; ++it) {
    const int f = it * 512 + tid;   // 0..4095 float4s over [m(128)][p4(32)]
    const int m = f >> 5;
    const int p0 = (f & 31) * 4;
    const float4 v = *(const float4*)(tok + tokbase + (size_t)m * 128 + p0);
    const int mi = (m & 31) * 4 + (m >> 5);
    const float vv[4] = {v.x, v.y, v.z, v.w};
#pragma unroll
    for (int jj = 0; jj < 4; ++jj) {
      const int p = p0 + jj;
      const int col = mi ^ (((p + (p >> 3)) & 7) << 2);
      tokT2[p * TOKR + col] = (_Float16)vv[jj];
    }
  }

  // ---- per-lane h fragments: h16[mh], m = mh*32 + l31, q0 = kh*16 + lh*8 ----
  half8 h16[4];
#pragma unroll
  for (int mh = 0; mh < 4; ++mh) {
    const int m = mh * 32 + l31;
    const int q0 = kh * 16 + lh * 8;
    const float4 v0 = *(const float4*)(tok + tokbase + (size_t)m * 128 + q0);
    const float4 v1 = *(const float4*)(tok + tokbase + (size_t)m * 128 + q0 + 4);
    h16[mh][0] = (_Float16)tanh_fast(v0.x);
    h16[mh][1] = (_Float16)tanh_fast(v0.y);
    h16[mh][2] = (_Float16)tanh_fast(v0.z);
    h16[mh][3] = (_Float16)tanh_fast(v0.w);
    h16[mh][4] = (_Float16)tanh_fast(v1.x);
    h16[mh][5] = (_Float16)tanh_fast(v1.y);
    h16[mh][6] = (_Float16)tanh_fast(v1.z);
    h16[mh][7] = (_Float16)tanh_fast(v1.w);
  }

  floatx16 acc[4][2];  // [mh][tt] -> 128 AGPRs
#pragma unroll
  for (int mh = 0; mh < 4; ++mh)
#pragma unroll
    for (int tt = 0; tt < 2; ++tt)
#pragma unroll
      for (int r = 0; r < 16; ++r) acc[mh][tt][r] = 0.f;

  __syncthreads();  // tokT2 + ring slots 0..5 ready (drains vmcnt)

  auto compute = [&](half8 (&bf)[2], half4t tk) {
#pragma unroll
    for (int mh = 0; mh < 4; ++mh) {
      half8 a = h16[mh] * tk[mh];   // 4 v_pk_mul each, feeds 2 MFMA
      acc[mh][0] = __builtin_amdgcn_mfma_f32_32x32x16_f16(a, bf[0], acc[mh][0], 0, 0, 0);
      acc[mh][1] = __builtin_amdgcn_mfma_f32_32x32x16_f16(a, bf[1], acc[mh][1], 0, 0, 0);
    }
  };

  half8 bfA[2], bfB[2];
  half4t tkA, tkB;
  readF(bfA, 0);  readT(tkA, 0);   // preload step 0

  // Steady loop: 21 iters x 6 sub-steps = steps 0..125. Per sub-step:
  // vmcnt(8) -> ds_read next step's frags+tk -> MFMA current -> DMA step+6.
  // Slots are static literals (zero per-step LDS address VALU).
#define SUBSTEP(s, BFC, TKC, BFN, TKN)      \
  {                                         \
    VM();                                   \
    readF(BFN, (s + 1) % 6);                \
    readT(TKN, P + s + 1);                  \
    compute(BFC, TKC);                      \
    issue(P + s + 6, s);                    \
  }
  for (int P = 0; P < 126; P += 6) {
    SUBSTEP(0, bfA, tkA, bfB, tkB);
    SUBSTEP(1, bfB, tkB, bfA, tkA);
    SUBSTEP(2, bfA, tkA, bfB, tkB);
    SUBSTEP(3, bfB, tkB, bfA, tkA);
    SUBSTEP(4, bfA, tkA, bfB, tkB);
    SUBSTEP(5, bfB, tkB, bfA, tkA);
  }
#undef SUBSTEP
  // Tail: step 126 (in bfA), then 127 (slot 1; vmcnt(8) = its 8 junk juniors)
  VM();
  readF(bfB, 1);  readT(tkB, 127);
  compute(bfA, tkA);   // p = 126
  compute(bfB, tkB);   // p = 127

  // ---- kh reduction: parity -> plane, 4 serial phases (2 waves/phase) ----
  // (red aliases tokT2+ring; barrier above this point drains all DMA writes)
  __syncthreads();
  {
    float* R = (kh & 1) ? red1 : red0;
    const int g = kh >> 1;
#pragma unroll
    for (int phase = 0; phase < 4; ++phase) {
      if (g == phase) {
#pragma unroll
        for (int mh = 0; mh < 4; ++mh)
#pragma unroll
          for (int tt = 0; tt < 2; ++tt) {
            const int t_loc = tt * 32 + l31;
#pragma unroll
            for (int r = 0; r < 16; ++r) {
              const int m_loc = mh * 32 + (r & 3) + 8 * (r >> 2) + 4 * lh;
              const int addr = m_loc * TN + t_loc;
              if (phase == 0) R[addr] = acc[mh][tt][r];
              else            R[addr] += acc[mh][tt][r];
            }
          }
      }
      __syncthreads();
    }
  }

  // ---- inline scatter epilogue: 512 threads, 16 m's x 1 t each ----
  const int t_loc = tid & 63;
  const int mgrp = tid >> 6;  // 0..7 (wave-uniform -> scalar heads/w_red loads)
  const int t = th * 64 + t_loc;
  const float bc = b_comp[t];
  const float tb = tanh_fast(bc);
#pragma unroll 4
  for (int mi = 0; mi < 16; ++mi) {
    const int m_loc = mi * 8 + mgrp;
    const int gm = mb * BM + m_loc;
    const int head = heads[gm];
    const float wr = w_red[gm & 2047];
    const float v = red0[m_loc * TN + t_loc] + red1[m_loc * TN + t_loc] + bc;
    atomicAdd(out + ((size_t)(gm >> 11) * S_LEN + head) * T_DIM + t,
              wr * (tanh_fast(v) - tb));
  }
}

// ---------------------------------------------------------------------------
extern "C" void kernel_launch(void* const* d_in, const int* in_sizes, int n_in,
                              void* d_out, int out_size, void* d_ws, size_t ws_size,
                              hipStream_t stream) {
  const float* tok    = (const float*)d_in[0];
  // d_in[1] = dep_embeddings: dead input (source bug), unused
  const int*   heads  = (const int*)d_in[2];
  const float* W      = (const float*)d_in[3];
  const float* b_comp = (const float*)d_in[4];
  const float* w_red  = (const float*)d_in[5];
  const float* b_red  = (const float*)d_in[6];
  float* out = (float*)d_out;

  _Float16* W16f = (_Float16*)d_ws;  // 4 MB, MFMA-fragment order

  prep_kernel<<<3072, 256, 0, stream>>>(W, w_red, b_comp, b_red, W16f, out);
  main_kernel<<<NBLK, 512, 0, stream>>>(tok, heads, W16f, b_comp, w_red, out);
}

// Round 5
// 150.965 us; speedup vs baseline: 1.0143x; 1.0143x over previous
//
#include <hip/hip_runtime.h>
#include <hip/hip_fp16.h>
#include <math.h>

// Problem constants (B=8, S=2048, T=128)
#define S_LEN 2048
#define T_DIM 128
#define BM 128               // tokens per block (m-range): Mt=4 m-tiles
#define TN 64                // output cols per block: Nt=2 t-tiles
#define NBLK 256             // (mb 0..127) x (th 0..1); th on bit0 -> XCD-pinned
#define TOKR 132             // tokT2 row stride in f16 (264 B)

typedef _Float16 half8 __attribute__((ext_vector_type(8)));
typedef _Float16 half4t __attribute__((ext_vector_type(4)));
typedef float floatx16 __attribute__((ext_vector_type(16)));

// Fast exact tanh: 1 - 2/(1+e^{2x})
__device__ __forceinline__ float tanh_fast(float x) {
  return 1.0f - __fdividef(2.0f, 1.0f + __expf(2.0f * x));
}

// ---------------------------------------------------------------------------
// Kernel A (grid 3072x256): fused prep:
//  blocks 0..1023  : W fp32 [t][p][q] -> W16f fp16 MFMA-fragment order
//  blocks 1024..3071: out[b,i,t] = sum(w_red)*tanh(b_comp[t]) + b_red
//  (R5: w_red reads coalesced: lane i reads w_red[i*256+tid])
// ---------------------------------------------------------------------------
__global__ __launch_bounds__(256) void prep_kernel(
    const float* __restrict__ W, const float* __restrict__ w_red,
    const float* __restrict__ b_comp, const float* __restrict__ b_red,
    _Float16* __restrict__ W16f, float* __restrict__ out) {
  const int blk = blockIdx.x;
  const int tid = threadIdx.x;
  if (blk < 1024) {
    const int t = blk >> 3;
    const int qh = (blk >> 2) & 1;
    const int it = blk & 3;
    const int tc = t >> 5, tl = t & 31;
    const int e8 = it * 256 + tid;        // 0..1023 over [p(128)][q-chunk(8)]
    const int p = e8 >> 3;
    const int q = qh * 64 + (e8 & 7) * 8;
    const float* src = W + (size_t)t * 16384 + (size_t)p * 128 + q;
    const float4 v0 = *(const float4*)src;
    const float4 v1 = *(const float4*)(src + 4);
    half8 h;
    h[0] = (_Float16)v0.x; h[1] = (_Float16)v0.y;
    h[2] = (_Float16)v0.z; h[3] = (_Float16)v0.w;
    h[4] = (_Float16)v1.x; h[5] = (_Float16)v1.y;
    h[6] = (_Float16)v1.z; h[7] = (_Float16)v1.w;
    const int kc = q >> 4, lh2 = (q >> 3) & 1;
    *(half8*)(W16f + ((size_t)((p * 4 + tc) * 8 + kc)) * 512 + lh2 * 256 + tl * 8) = h;
  } else {
    __shared__ float red4[4];
    float part = 0.f;
#pragma unroll
    for (int i = 0; i < 8; ++i) part += w_red[i * 256 + tid];   // coalesced
#pragma unroll
    for (int off = 32; off > 0; off >>= 1) part += __shfl_down(part, off, 64);
    if ((tid & 63) == 0) red4[tid >> 6] = part;
    __syncthreads();
    const float Sw = red4[0] + red4[1] + red4[2] + red4[3];
    const float br = b_red[0];
    const size_t base = (size_t)(blk - 1024) * 1024 + (size_t)tid * 4;
    const int t0 = (int)(base & 127);
    float4 v;
    v.x = Sw * tanh_fast(b_comp[t0 + 0]) + br;
    v.y = Sw * tanh_fast(b_comp[t0 + 1]) + br;
    v.z = Sw * tanh_fast(b_comp[t0 + 2]) + br;
    v.w = Sw * tanh_fast(b_comp[t0 + 3]) + br;
    *(float4*)(out + base) = v;
  }
}

// ---------------------------------------------------------------------------
// Kernel B: MFMA main, BM=128 x TN=64 (Mt=4, Nt=2), DECOUPLED SCHEDULE.
// R5 THEORY: R1-R4 falsified BW (traffic halved: flat), occupancy (waves
// halved: flat), and latency (counted-vmcnt depth-6 LDS ring: flat).
// Invariant across all: substep ~1350cyc, MfmaUtil 42-46, VALUBusy ~28.
// Common structure never varied: A-operand built by pk_mul from a ds_read
// of the SAME substep, MFMA consuming it immediately -> per-substep serial
// chain lgkm(tk) -> 16 pk_mul -> 8 MFMA with zero producer/consumer slack.
// Fix: one-substep lookahead for a-frags. Substep k:
//   [setprio(1)] 8 dependency-free MFMAs (a(k) built @k-1, bf(k) loaded @k-2)
//   [setprio(0)] issue bf(k+2) global + tk(k+2) ds_read
//   build a(k+1) from tk(k+1)  (one substep of lgkm slack; pk_muls fill the
//   matrix-pipe shadow -- independent of this substep's MFMAs)
// 6-substep unroll (bf/tk 3-rotation x2, a 2-rotation x3). Ring dropped
// (R4 null). red aliases tokT2 (all tk reads precede the post-loop barrier).
// 1 block/CU, 2 waves/SIMD; acc = 8 floatx16 = 128 AGPR.
// v_mfma_f32_32x32x16_f16: A lane m=l&31, k=(l>>5)*8+j; B n=l&31 same k;
// C/D col=l&31, row=(r&3)+8*(r>>2)+4*(l>>5)   [m74/m101-verified]
// ---------------------------------------------------------------------------
__global__ __launch_bounds__(512, 2) void main_kernel(
    const float* __restrict__ tok, const int* __restrict__ heads,
    const _Float16* __restrict__ W16f, const float* __restrict__ b_comp,
    const float* __restrict__ w_red, float* __restrict__ out) {
  __shared__ __align__(16) char smem[65536];   // 64 KB: tokT2 (34K) / red alias
  _Float16* const tokT2 = (_Float16*)smem;     // [p][(mi ^ swz(p))]
  float* const red0 = (float*)smem;            // epilogue alias, plane 0 (32 KB)
  float* const red1 = (float*)smem + BM * TN;  // plane 1 (32 KB)

  const int tid = threadIdx.x;
  const int lane = tid & 63;
  const int kh = tid >> 6;   // wave = q-chunk of 16 (kc index)
  const int l31 = lane & 31;
  const int lh = lane >> 5;
  const int blk = blockIdx.x;
  const int th = blk & 1;                 // t-half, bit0 (XCD-pinned: XCD=blk&7)
  const int mb = blk >> 1;                // 0..127
  // Full-rank p-phase stagger per XCD (L2 decorrelation, R1-proven)
  const int pstag = ((blk >> 3) * 4) & 127;
  const size_t tokbase = (size_t)mb * BM * T_DIM;

  // Wave's B-fragment offsets: tc = th*2 + tt, kc = kh
  int off[2];
#pragma unroll
  for (int tt = 0; tt < 2; ++tt)
    off[tt] = (((th * 2 + tt) * 8 + kh) << 9) + lane * 8;

  half8 bf0[2], bf1[2], bf2[2];
  half4t tk0, tk1, tk2;
  half8 aA[4], aB[4];
  half8 h16[4];

  auto loadB = [&](half8 (&bf)[2], int p) {
    const int pp = (p + pstag) & 127;
    const _Float16* wp = W16f + (size_t)pp * 16384;
    bf[0] = *(const half8*)(wp + off[0]);
    bf[1] = *(const half8*)(wp + off[1]);
  };
  auto loadT = [&](half4t& tk, int p) {
    const int pp = (p + pstag) & 127;
    const int col = (l31 * 4) ^ (((pp + (pp >> 3)) & 7) << 2);
    tk = *(const half4t*)(tokT2 + pp * TOKR + col);
  };
  auto build = [&](half8 (&a)[4], half4t tk) {
#pragma unroll
    for (int mh = 0; mh < 4; ++mh) a[mh] = h16[mh] * tk[mh];  // 4 pk_mul each
  };

  // First two W16f fragment loads issue before the barrier: L2 latency
  // overlaps the LDS staging drain.
  loadB(bf0, 0);
  loadB(bf1, 1);

  // ---- stage tokT2: coalesced float4 reads, swizzled transposed f16 writes --
#pragma unroll
  for (int it = 0; it < 8; ++it) {
    const int f = it * 512 + tid;   // 0..4095 float4s over [m(128)][p4(32)]
    const int m = f >> 5;
    const int p0 = (f & 31) * 4;
    const float4 v = *(const float4*)(tok + tokbase + (size_t)m * 128 + p0);
    const int mi = (m & 31) * 4 + (m >> 5);
    const float vv[4] = {v.x, v.y, v.z, v.w};
#pragma unroll
    for (int jj = 0; jj < 4; ++jj) {
      const int p = p0 + jj;
      const int col = mi ^ (((p + (p >> 3)) & 7) << 2);
      tokT2[p * TOKR + col] = (_Float16)vv[jj];
    }
  }

  // ---- per-lane h fragments: h16[mh], m = mh*32 + l31, q0 = kh*16 + lh*8 ----
#pragma unroll
  for (int mh = 0; mh < 4; ++mh) {
    const int m = mh * 32 + l31;
    const int q0 = kh * 16 + lh * 8;
    const float4 v0 = *(const float4*)(tok + tokbase + (size_t)m * 128 + q0);
    const float4 v1 = *(const float4*)(tok + tokbase + (size_t)m * 128 + q0 + 4);
    h16[mh][0] = (_Float16)tanh_fast(v0.x);
    h16[mh][1] = (_Float16)tanh_fast(v0.y);
    h16[mh][2] = (_Float16)tanh_fast(v0.z);
    h16[mh][3] = (_Float16)tanh_fast(v0.w);
    h16[mh][4] = (_Float16)tanh_fast(v1.x);
    h16[mh][5] = (_Float16)tanh_fast(v1.y);
    h16[mh][6] = (_Float16)tanh_fast(v1.z);
    h16[mh][7] = (_Float16)tanh_fast(v1.w);
  }

  floatx16 acc[4][2];  // [mh][tt] -> 128 AGPRs
#pragma unroll
  for (int mh = 0; mh < 4; ++mh)
#pragma unroll
    for (int tt = 0; tt < 2; ++tt)
#pragma unroll
      for (int r = 0; r < 16; ++r) acc[mh][tt][r] = 0.f;

  __syncthreads();  // tokT2 ready; last barrier before the p-loop

  auto mfma8 = [&](half8 (&a)[4], half8 (&bf)[2]) {
    __builtin_amdgcn_s_setprio(1);
#pragma unroll
    for (int mh = 0; mh < 4; ++mh) {
      acc[mh][0] = __builtin_amdgcn_mfma_f32_32x32x16_f16(a[mh], bf[0], acc[mh][0], 0, 0, 0);
      acc[mh][1] = __builtin_amdgcn_mfma_f32_32x32x16_f16(a[mh], bf[1], acc[mh][1], 0, 0, 0);
    }
    __builtin_amdgcn_s_setprio(0);
  };

  // Pipeline prologue: tk(0),tk(1) ds_reads; a(0) built from tk(0).
  loadT(tk0, 0);
  loadT(tk1, 1);
  build(aA, tk0);

  // Substep k: MFMA(a(k), bf(k)); issue bf(k+2), tk(k+2); build a(k+1).
  // Rotations: bf[k%3], tk[(k+1)%3]=next, tk[(k+2)%3]=prefetch, a 2-cycle.
#define SUBSTEP(BF_CUR, BF_PRE, TK_NXT, TK_PRE, A_CUR, A_NXT, K) \
  {                                                              \
    mfma8(A_CUR, BF_CUR);                                        \
    loadB(BF_PRE, (K) + 2);                                      \
    loadT(TK_PRE, (K) + 2);                                      \
    build(A_NXT, TK_NXT);                                        \
  }
  for (int p = 0; p < 126; p += 6) {
    SUBSTEP(bf0, bf2, tk1, tk2, aA, aB, p + 0);
    SUBSTEP(bf1, bf0, tk2, tk0, aB, aA, p + 1);
    SUBSTEP(bf2, bf1, tk0, tk1, aA, aB, p + 2);
    SUBSTEP(bf0, bf2, tk1, tk2, aB, aA, p + 3);
    SUBSTEP(bf1, bf0, tk2, tk0, aA, aB, p + 4);
    SUBSTEP(bf2, bf1, tk0, tk1, aB, aA, p + 5);
  }
#undef SUBSTEP
  // Tail: p=126 (aA built @125 from tk0=tk(126); bf0 loaded @124),
  //       p=127 (a from tk1=tk(127) loaded @125; bf1 loaded @125).
  mfma8(aA, bf0);        // p = 126
  build(aB, tk1);
  mfma8(aB, bf1);        // p = 127

  // ---- kh reduction: parity -> plane, 4 serial phases (2 waves/phase) ----
  // (red aliases tokT2; the barrier below orders all tk reads before writes)
  __syncthreads();
  {
    float* R = (kh & 1) ? red1 : red0;
    const int g = kh >> 1;
#pragma unroll
    for (int phase = 0; phase < 4; ++phase) {
      if (g == phase) {
#pragma unroll
        for (int mh = 0; mh < 4; ++mh)
#pragma unroll
          for (int tt = 0; tt < 2; ++tt) {
            const int t_loc = tt * 32 + l31;
#pragma unroll
            for (int r = 0; r < 16; ++r) {
              const int m_loc = mh * 32 + (r & 3) + 8 * (r >> 2) + 4 * lh;
              const int addr = m_loc * TN + t_loc;
              if (phase == 0) R[addr] = acc[mh][tt][r];
              else            R[addr] += acc[mh][tt][r];
            }
          }
      }
      __syncthreads();
    }
  }

  // ---- inline scatter epilogue: 512 threads, 16 m's x 1 t each ----
  const int t_loc = tid & 63;
  const int mgrp = tid >> 6;  // 0..7 (wave-uniform -> scalar heads/w_red loads)
  const int t = th * 64 + t_loc;
  const float bc = b_comp[t];
  const float tb = tanh_fast(bc);
#pragma unroll 4
  for (int mi = 0; mi < 16; ++mi) {
    const int m_loc = mi * 8 + mgrp;
    const int gm = mb * BM + m_loc;
    const int head = heads[gm];
    const float wr = w_red[gm & 2047];
    const float v = red0[m_loc * TN + t_loc] + red1[m_loc * TN + t_loc] + bc;
    atomicAdd(out + ((size_t)(gm >> 11) * S_LEN + head) * T_DIM + t,
              wr * (tanh_fast(v) - tb));
  }
}

// ---------------------------------------------------------------------------
extern "C" void kernel_launch(void* const* d_in, const int* in_sizes, int n_in,
                              void* d_out, int out_size, void* d_ws, size_t ws_size,
                              hipStream_t stream) {
  const float* tok    = (const float*)d_in[0];
  // d_in[1] = dep_embeddings: dead input (source bug), unused
  const int*   heads  = (const int*)d_in[2];
  const float* W      = (const float*)d_in[3];
  const float* b_comp = (const float*)d_in[4];
  const float* w_red  = (const float*)d_in[5];
  const float* b_red  = (const float*)d_in[6];
  float* out = (float*)d_out;

  _Float16* W16f = (_Float16*)d_ws;  // 4 MB, MFMA-fragment order

  prep_kernel<<<3072, 256, 0, stream>>>(W, w_red, b_comp, b_red, W16f, out);
  main_kernel<<<NBLK, 512, 0, stream>>>(tok, heads, W16f, b_comp, w_red, out);
}

// Round 6
// 150.625 us; speedup vs baseline: 1.0166x; 1.0023x over previous
//
#include <hip/hip_runtime.h>
#include <hip/hip_fp16.h>
#include <math.h>

// Problem constants (B=8, S=2048, T=128)
#define S_LEN 2048
#define T_DIM 128
#define BM 128               // tokens per block (m-range): Mt=4 m-tiles
#define TN 64                // output cols per block: Nt=2 t-tiles
#define NBLK 256             // (mb 0..127) x (th 0..1); th on bit0 -> XCD-pinned
#define TOKR 132             // tokT2 row stride in f16 (264 B)

typedef _Float16 half8 __attribute__((ext_vector_type(8)));
typedef _Float16 half4t __attribute__((ext_vector_type(4)));
typedef float floatx16 __attribute__((ext_vector_type(16)));

// Fast exact tanh: 1 - 2/(1+e^{2x})
__device__ __forceinline__ float tanh_fast(float x) {
  return 1.0f - __fdividef(2.0f, 1.0f + __expf(2.0f * x));
}

// ---------------------------------------------------------------------------
// Kernel A (grid 3072x256): fused prep:
//  blocks 0..1023  : W fp32 [t][p][q] -> W16f fp16 MFMA-fragment order
//  blocks 1024..3071: out[b,i,t] = sum(w_red)*tanh(b_comp[t]) + b_red
// ---------------------------------------------------------------------------
__global__ __launch_bounds__(256) void prep_kernel(
    const float* __restrict__ W, const float* __restrict__ w_red,
    const float* __restrict__ b_comp, const float* __restrict__ b_red,
    _Float16* __restrict__ W16f, float* __restrict__ out) {
  const int blk = blockIdx.x;
  const int tid = threadIdx.x;
  if (blk < 1024) {
    const int t = blk >> 3;
    const int qh = (blk >> 2) & 1;
    const int it = blk & 3;
    const int tc = t >> 5, tl = t & 31;
    const int e8 = it * 256 + tid;        // 0..1023 over [p(128)][q-chunk(8)]
    const int p = e8 >> 3;
    const int q = qh * 64 + (e8 & 7) * 8;
    const float* src = W + (size_t)t * 16384 + (size_t)p * 128 + q;
    const float4 v0 = *(const float4*)src;
    const float4 v1 = *(const float4*)(src + 4);
    half8 h;
    h[0] = (_Float16)v0.x; h[1] = (_Float16)v0.y;
    h[2] = (_Float16)v0.z; h[3] = (_Float16)v0.w;
    h[4] = (_Float16)v1.x; h[5] = (_Float16)v1.y;
    h[6] = (_Float16)v1.z; h[7] = (_Float16)v1.w;
    const int kc = q >> 4, lh2 = (q >> 3) & 1;
    *(half8*)(W16f + ((size_t)((p * 4 + tc) * 8 + kc)) * 512 + lh2 * 256 + tl * 8) = h;
  } else {
    __shared__ float red4[4];
    float part = 0.f;
#pragma unroll
    for (int i = 0; i < 8; ++i) part += w_red[i * 256 + tid];   // coalesced
#pragma unroll
    for (int off = 32; off > 0; off >>= 1) part += __shfl_down(part, off, 64);
    if ((tid & 63) == 0) red4[tid >> 6] = part;
    __syncthreads();
    const float Sw = red4[0] + red4[1] + red4[2] + red4[3];
    const float br = b_red[0];
    const size_t base = (size_t)(blk - 1024) * 1024 + (size_t)tid * 4;
    const int t0 = (int)(base & 127);
    float4 v;
    v.x = Sw * tanh_fast(b_comp[t0 + 0]) + br;
    v.y = Sw * tanh_fast(b_comp[t0 + 1]) + br;
    v.z = Sw * tanh_fast(b_comp[t0 + 2]) + br;
    v.w = Sw * tanh_fast(b_comp[t0 + 3]) + br;
    *(float4*)(out + base) = v;
  }
}

// ---------------------------------------------------------------------------
// Kernel B: MFMA main, BM=128 x TN=64 (Mt=4, Nt=2), WAVE-DEPHASED p-loop.
// R6 THEORY (single-variable A/B vs R5): R1-R5 falsified BW, occupancy,
// latency-depth, and source-order scheduling; invariant ~1390 cyc/step vs
// 517 cyc MFMA floor per SIMD, with ~500 cyc/step of no-runnable-wave wait.
// The never-varied variable: all 8 waves run the SAME p-sequence in
// lockstep (same barrier release, identical instruction stream) -> the 2
// waves sharing a SIMD hit their per-step waits SIMULTANEOUSLY -> SIMD
// idles instead of covering one wave's wait with the other's MFMA cluster.
// Fix: per-WAVE p-phase offset (pstag += kh*16): SIMD-mates run ~16 steps
// (~22K cyc) apart; their MFMA/wait phases decorrelate. fp32 p-order
// reorder only; no sync structure change; W16f window still L2-resident.
// 1 block/CU, 2 waves/SIMD; acc = 8 floatx16 = 128 AGPR (unified).
// v_mfma_f32_32x32x16_f16: A lane m=l&31, k=(l>>5)*8+j; B n=l&31 same k;
// C/D col=l&31, row=(r&3)+8*(r>>2)+4*(l>>5)   [m74/m101-verified]
// ---------------------------------------------------------------------------
__global__ __launch_bounds__(512, 2) void main_kernel(
    const float* __restrict__ tok, const int* __restrict__ heads,
    const _Float16* __restrict__ W16f, const float* __restrict__ b_comp,
    const float* __restrict__ w_red, float* __restrict__ out) {
  __shared__ __align__(16) char smem[65536];   // 64 KB: tokT2 (34K) / red alias
  _Float16* const tokT2 = (_Float16*)smem;     // [p][(mi ^ swz(p))]
  float* const red0 = (float*)smem;            // epilogue alias, plane 0 (32 KB)
  float* const red1 = (float*)smem + BM * TN;  // plane 1 (32 KB)

  const int tid = threadIdx.x;
  const int lane = tid & 63;
  const int kh = tid >> 6;   // wave = q-chunk of 16 (kc index)
  const int l31 = lane & 31;
  const int lh = lane >> 5;
  const int blk = blockIdx.x;
  const int th = blk & 1;                 // t-half, bit0 (XCD-pinned: XCD=blk&7)
  const int mb = blk >> 1;                // 0..127
  // p-phase stagger: block-level full-rank per XCD (R1-proven) PLUS
  // per-WAVE de-phasing (kh*16): SIMD-mates ~16 steps apart.
  const int pstag = (((blk >> 3) * 4) + kh * 16) & 127;
  const size_t tokbase = (size_t)mb * BM * T_DIM;

  // Wave's B-fragment offsets: tc = th*2 + tt, kc = kh
  int off[2];
#pragma unroll
  for (int tt = 0; tt < 2; ++tt)
    off[tt] = (((th * 2 + tt) * 8 + kh) << 9) + lane * 8;

  half8 bf0[2], bf1[2], bf2[2];
  half4t tk0, tk1, tk2;
  half8 aA[4], aB[4];
  half8 h16[4];

  auto loadB = [&](half8 (&bf)[2], int p) {
    const int pp = (p + pstag) & 127;
    const _Float16* wp = W16f + (size_t)pp * 16384;
    bf[0] = *(const half8*)(wp + off[0]);
    bf[1] = *(const half8*)(wp + off[1]);
  };
  auto loadT = [&](half4t& tk, int p) {
    const int pp = (p + pstag) & 127;
    const int col = (l31 * 4) ^ (((pp + (pp >> 3)) & 7) << 2);
    tk = *(const half4t*)(tokT2 + pp * TOKR + col);
  };
  auto build = [&](half8 (&a)[4], half4t tk) {
#pragma unroll
    for (int mh = 0; mh < 4; ++mh) a[mh] = h16[mh] * tk[mh];  // 4 pk_mul each
  };

  // First two W16f fragment loads issue before the barrier: L2 latency
  // overlaps the LDS staging drain.
  loadB(bf0, 0);
  loadB(bf1, 1);

  // ---- stage tokT2: coalesced float4 reads, swizzled transposed f16 writes --
#pragma unroll
  for (int it = 0; it < 8; ++it) {
    const int f = it * 512 + tid;   // 0..4095 float4s over [m(128)][p4(32)]
    const int m = f >> 5;
    const int p0 = (f & 31) * 4;
    const float4 v = *(const float4*)(tok + tokbase + (size_t)m * 128 + p0);
    const int mi = (m & 31) * 4 + (m >> 5);
    const float vv[4] = {v.x, v.y, v.z, v.w};
#pragma unroll
    for (int jj = 0; jj < 4; ++jj) {
      const int p = p0 + jj;
      const int col = mi ^ (((p + (p >> 3)) & 7) << 2);
      tokT2[p * TOKR + col] = (_Float16)vv[jj];
    }
  }

  // ---- per-lane h fragments: h16[mh], m = mh*32 + l31, q0 = kh*16 + lh*8 ----
#pragma unroll
  for (int mh = 0; mh < 4; ++mh) {
    const int m = mh * 32 + l31;
    const int q0 = kh * 16 + lh * 8;
    const float4 v0 = *(const float4*)(tok + tokbase + (size_t)m * 128 + q0);
    const float4 v1 = *(const float4*)(tok + tokbase + (size_t)m * 128 + q0 + 4);
    h16[mh][0] = (_Float16)tanh_fast(v0.x);
    h16[mh][1] = (_Float16)tanh_fast(v0.y);
    h16[mh][2] = (_Float16)tanh_fast(v0.z);
    h16[mh][3] = (_Float16)tanh_fast(v0.w);
    h16[mh][4] = (_Float16)tanh_fast(v1.x);
    h16[mh][5] = (_Float16)tanh_fast(v1.y);
    h16[mh][6] = (_Float16)tanh_fast(v1.z);
    h16[mh][7] = (_Float16)tanh_fast(v1.w);
  }

  floatx16 acc[4][2];  // [mh][tt] -> 128 AGPRs
#pragma unroll
  for (int mh = 0; mh < 4; ++mh)
#pragma unroll
    for (int tt = 0; tt < 2; ++tt)
#pragma unroll
      for (int r = 0; r < 16; ++r) acc[mh][tt][r] = 0.f;

  __syncthreads();  // tokT2 ready; last barrier before the p-loop

  auto mfma8 = [&](half8 (&a)[4], half8 (&bf)[2]) {
    __builtin_amdgcn_s_setprio(1);
#pragma unroll
    for (int mh = 0; mh < 4; ++mh) {
      acc[mh][0] = __builtin_amdgcn_mfma_f32_32x32x16_f16(a[mh], bf[0], acc[mh][0], 0, 0, 0);
      acc[mh][1] = __builtin_amdgcn_mfma_f32_32x32x16_f16(a[mh], bf[1], acc[mh][1], 0, 0, 0);
    }
    __builtin_amdgcn_s_setprio(0);
  };

  // Pipeline prologue: tk(0),tk(1) ds_reads; a(0) built from tk(0).
  loadT(tk0, 0);
  loadT(tk1, 1);
  build(aA, tk0);

  // Substep k: MFMA(a(k), bf(k)); issue bf(k+2), tk(k+2); build a(k+1).
  // Rotations: bf[k%3], tk[(k+1)%3]=next, tk[(k+2)%3]=prefetch, a 2-cycle.
#define SUBSTEP(BF_CUR, BF_PRE, TK_NXT, TK_PRE, A_CUR, A_NXT, K) \
  {                                                              \
    mfma8(A_CUR, BF_CUR);                                        \
    loadB(BF_PRE, (K) + 2);                                      \
    loadT(TK_PRE, (K) + 2);                                      \
    build(A_NXT, TK_NXT);                                        \
  }
  for (int p = 0; p < 126; p += 6) {
    SUBSTEP(bf0, bf2, tk1, tk2, aA, aB, p + 0);
    SUBSTEP(bf1, bf0, tk2, tk0, aB, aA, p + 1);
    SUBSTEP(bf2, bf1, tk0, tk1, aA, aB, p + 2);
    SUBSTEP(bf0, bf2, tk1, tk2, aB, aA, p + 3);
    SUBSTEP(bf1, bf0, tk2, tk0, aA, aB, p + 4);
    SUBSTEP(bf2, bf1, tk0, tk1, aB, aA, p + 5);
  }
#undef SUBSTEP
  // Tail: p=126 (aA built @125 from tk0=tk(126); bf0 loaded @124),
  //       p=127 (a from tk1=tk(127) loaded @125; bf1 loaded @125).
  mfma8(aA, bf0);        // p = 126
  build(aB, tk1);
  mfma8(aB, bf1);        // p = 127

  // ---- kh reduction: parity -> plane, 4 serial phases (2 waves/phase) ----
  // (red aliases tokT2; the barrier below orders all tk reads before writes)
  __syncthreads();
  {
    float* R = (kh & 1) ? red1 : red0;
    const int g = kh >> 1;
#pragma unroll
    for (int phase = 0; phase < 4; ++phase) {
      if (g == phase) {
#pragma unroll
        for (int mh = 0; mh < 4; ++mh)
#pragma unroll
          for (int tt = 0; tt < 2; ++tt) {
            const int t_loc = tt * 32 + l31;
#pragma unroll
            for (int r = 0; r < 16; ++r) {
              const int m_loc = mh * 32 + (r & 3) + 8 * (r >> 2) + 4 * lh;
              const int addr = m_loc * TN + t_loc;
              if (phase == 0) R[addr] = acc[mh][tt][r];
              else            R[addr] += acc[mh][tt][r];
            }
          }
      }
      __syncthreads();
    }
  }

  // ---- inline scatter epilogue: 512 threads, 16 m's x 1 t each ----
  const int t_loc = tid & 63;
  const int mgrp = tid >> 6;  // 0..7 (wave-uniform -> scalar heads/w_red loads)
  const int t = th * 64 + t_loc;
  const float bc = b_comp[t];
  const float tb = tanh_fast(bc);
#pragma unroll 4
  for (int mi = 0; mi < 16; ++mi) {
    const int m_loc = mi * 8 + mgrp;
    const int gm = mb * BM + m_loc;
    const int head = heads[gm];
    const float wr = w_red[gm & 2047];
    const float v = red0[m_loc * TN + t_loc] + red1[m_loc * TN + t_loc] + bc;
    atomicAdd(out + ((size_t)(gm >> 11) * S_LEN + head) * T_DIM + t,
              wr * (tanh_fast(v) - tb));
  }
}

// ---------------------------------------------------------------------------
extern "C" void kernel_launch(void* const* d_in, const int* in_sizes, int n_in,
                              void* d_out, int out_size, void* d_ws, size_t ws_size,
                              hipStream_t stream) {
  const float* tok    = (const float*)d_in[0];
  // d_in[1] = dep_embeddings: dead input (source bug), unused
  const int*   heads  = (const int*)d_in[2];
  const float* W      = (const float*)d_in[3];
  const float* b_comp = (const float*)d_in[4];
  const float* w_red  = (const float*)d_in[5];
  const float* b_red  = (const float*)d_in[6];
  float* out = (float*)d_out;

  _Float16* W16f = (_Float16*)d_ws;  // 4 MB, MFMA-fragment order

  prep_kernel<<<3072, 256, 0, stream>>>(W, w_red, b_comp, b_red, W16f, out);
  main_kernel<<<NBLK, 512, 0, stream>>>(tok, heads, W16f, b_comp, w_red, out);
}